// Round 1
// baseline (962.001 us; speedup 1.0000x reference)
//
#include <hip/hip_runtime.h>
#include <hip/hip_bf16.h>
#include <math.h>

#define NTOK 384
#define HEADS 4

typedef __attribute__((ext_vector_type(8))) short bf16x8;
typedef __attribute__((ext_vector_type(4))) float f32x4;

__device__ __forceinline__ unsigned short f2b(float f) {
    union { float f; unsigned int u; } v; v.f = f;
    unsigned int r = (v.u + 0x7fff + ((v.u >> 16) & 1)) >> 16;  // RNE
    return (unsigned short)r;
}

// packed fp32 pair -> bf16x2 (RNE); compiler lowers to v_cvt_pk_bf16_f32
__device__ __forceinline__ unsigned int cvt2(float a, float b) {
    __hip_bfloat162 h = __float22bfloat162_rn(make_float2(a, b));
    unsigned int u;
    __builtin_memcpy(&u, &h, 4);
    return u;
}

// async 16B global -> LDS (wave-uniform LDS base; HW adds lane*16)
__device__ __forceinline__ void g2l16(const void* g, void* l) {
    __builtin_amdgcn_global_load_lds(
        (const __attribute__((address_space(1))) unsigned int*)g,
        (__attribute__((address_space(3))) unsigned int*)l, 16, 0, 0);
}

// ---------------------------------------------------------------------------
// 64x64-tile MFMA bf16 GEMM, batched over z. C = A@B^T + bias, opt relu,
// fp32/bf16 out, optional transposed-V epilogue for col0 >= dv2.
// Block 256 thr = 4 waves (2x2, 32x32 each). BK=32, double-buffered LDS.
// A: bf16, staged via global_load_lds. B: bf16 (same path) OR fp32 weights
// (bf32=1): reg-staged (issue loads early, cvt_pk+ds_write after MFMAs) so
// the fp32->bf16 conversion is fused into staging — no separate convert pass.
// 64B LDS rows, 16B chunks rotated by (row>>1)&3.
// ---------------------------------------------------------------------------
__device__ __forceinline__ void stage64(
    const unsigned short* __restrict__ g, int row0, int k0, int ld,
    char* region, int wid, int lane)
{
    int c = wid * 64 + lane;                 // chunk 0..255
    int row = c >> 2, p = c & 3;
    int kc = (p - (row >> 1)) & 3;
    g2l16(g + (long)(row0 + row) * ld + k0 + kc * 8,
          region + (wid * 64) * 16);         // wave-uniform base
}

__global__ __launch_bounds__(256, 4) void gemm64(
    const unsigned short* __restrict__ A, const void* __restrict__ Bv,
    const float* __restrict__ bias, void* __restrict__ Cv,
    int K, int lda, int ldb, int ldc,
    long sA, long sB, long sC, int relu, int out_bf16,
    unsigned short* __restrict__ vt, int dv2, int bf32)
{
    __shared__ char smem[2][8192];           // per buf: A 4KB | B 4KB
    A += (long)blockIdx.z * sA;
    const int t = threadIdx.x, lane = t & 63, wid = t >> 6;
    const int wm = wid >> 1, wn = wid & 1;
    const int r16 = lane & 15, quad = lane >> 4;
    const int row0 = blockIdx.y * 64, col0 = blockIdx.x * 64;

    // staging coords (same rotated layout for both B paths)
    const int c = wid * 64 + lane;
    const int srow = c >> 2, sp = c & 3;
    const int skc = (sp - (srow >> 1)) & 3;

    const unsigned short* B16 = nullptr;
    const float* B32 = nullptr;
    if (bf32) B32 = (const float*)Bv + (long)(col0 + srow) * ldb + skc * 8;
    else      B16 = (const unsigned short*)Bv + (long)blockIdx.z * sB;

    f32x4 acc[2][2] = {};
    float4 pv0, pv1;

    // prologue: stage tile 0
    if (bf32) {
        pv0 = *reinterpret_cast<const float4*>(B32);
        pv1 = *reinterpret_cast<const float4*>(B32 + 4);
    } else {
        stage64(B16, col0, 0, ldb, smem[0] + 4096, wid, lane);
    }
    stage64(A, row0, 0, lda, smem[0], wid, lane);
    if (bf32) {
        uint4 o;
        o.x = cvt2(pv0.x, pv0.y); o.y = cvt2(pv0.z, pv0.w);
        o.z = cvt2(pv1.x, pv1.y); o.w = cvt2(pv1.z, pv1.w);
        *reinterpret_cast<uint4*>(smem[0] + 4096 + c * 16) = o;
    }
    int buf = 0;

    for (int k0 = 0; k0 < K; k0 += 32) {
        __syncthreads();
        const int more = (k0 + 32 < K);
        if (more) {
            if (bf32) {                       // issue B loads first: ds_write
                pv0 = *reinterpret_cast<const float4*>(B32 + k0 + 32);
                pv1 = *reinterpret_cast<const float4*>(B32 + k0 + 36);
            } else {
                stage64(B16, col0, k0 + 32, ldb, smem[buf ^ 1] + 4096, wid, lane);
            }
            stage64(A, row0, k0 + 32, lda, smem[buf ^ 1], wid, lane);
        }
        const char* cb = smem[buf];
        bf16x8 af[2], bfv[2];
        #pragma unroll
        for (int rt = 0; rt < 2; ++rt) {
            int row = wm * 32 + rt * 16 + r16;
            int p = (quad + (row >> 1)) & 3;
            af[rt] = *reinterpret_cast<const bf16x8*>(cb + row * 64 + p * 16);
        }
        #pragma unroll
        for (int ct = 0; ct < 2; ++ct) {
            int col = wn * 32 + ct * 16 + r16;
            int p = (quad + (col >> 1)) & 3;
            bfv[ct] = *reinterpret_cast<const bf16x8*>(cb + 4096 + col * 64 + p * 16);
        }
        #pragma unroll
        for (int rt = 0; rt < 2; ++rt)
            #pragma unroll
            for (int ct = 0; ct < 2; ++ct)
                acc[rt][ct] = __builtin_amdgcn_mfma_f32_16x16x32_bf16(
                    af[rt], bfv[ct], acc[rt][ct], 0, 0, 0);
        // write-late half of the reg-staged B path: waits only on the two
        // B loads (vmcnt leaves the A global_load_lds in flight)
        if (more && bf32) {
            uint4 o;
            o.x = cvt2(pv0.x, pv0.y); o.y = cvt2(pv0.z, pv0.w);
            o.z = cvt2(pv1.x, pv1.y); o.w = cvt2(pv1.z, pv1.w);
            *reinterpret_cast<uint4*>(smem[buf ^ 1] + 4096 + c * 16) = o;
        }
        buf ^= 1;
    }

    float* Cf = (float*)Cv;
    unsigned short* Cb = (unsigned short*)Cv;
    const long zoff = (long)blockIdx.z * sC;
    const int vwrite = (vt != nullptr) && (col0 >= dv2);
    #pragma unroll
    for (int rt = 0; rt < 2; ++rt) {
        #pragma unroll
        for (int ct = 0; ct < 2; ++ct) {
            f32x4 v = acc[rt][ct];
            int col = col0 + wn * 32 + ct * 16 + r16;
            float bi = bias ? bias[col] : 0.f;
            #pragma unroll
            for (int i = 0; i < 4; ++i) {
                v[i] += bi;
                if (relu) v[i] = fmaxf(v[i], 0.f);
            }
            int rbase = row0 + wm * 32 + rt * 16 + quad * 4;
            if (vwrite) {
                ushort4 p;
                p.x = f2b(v[0]); p.y = f2b(v[1]); p.z = f2b(v[2]); p.w = f2b(v[3]);
                *reinterpret_cast<ushort4*>(vt + (long)(col - dv2) * NTOK + rbase) = p;
            } else if (out_bf16) {
                #pragma unroll
                for (int i = 0; i < 4; ++i)
                    Cb[zoff + (long)(rbase + i) * ldc + col] = f2b(v[i]);
            } else {
                #pragma unroll
                for (int i = 0; i < 4; ++i)
                    Cf[zoff + (long)(rbase + i) * ldc + col] = v[i];
            }
        }
    }
}

// ---------------------------------------------------------------------------
// Softmax over rows of length 384 (one wave per row); fp32 in, bf16 out.
// ---------------------------------------------------------------------------
__global__ __launch_bounds__(64) void softmax_rows(
    const float* __restrict__ S, unsigned short* __restrict__ P, float scale)
{
    const float* p = S + (long)blockIdx.x * NTOK;
    unsigned short* q = P + (long)blockIdx.x * NTOK;
    const int t = threadIdx.x;
    float vals[6];
    float vmax = -1e30f;
    #pragma unroll
    for (int i = 0; i < 6; ++i) {
        vals[i] = p[t + i * 64] * scale;
        vmax = fmaxf(vmax, vals[i]);
    }
    for (int off = 32; off; off >>= 1) vmax = fmaxf(vmax, __shfl_down(vmax, off));
    vmax = __shfl(vmax, 0);
    float sum = 0.f;
    #pragma unroll
    for (int i = 0; i < 6; ++i) { vals[i] = __expf(vals[i] - vmax); sum += vals[i]; }
    for (int off = 32; off; off >>= 1) sum += __shfl_down(sum, off);
    sum = __shfl(sum, 0);
    float inv = 1.f / sum;
    #pragma unroll
    for (int i = 0; i < 6; ++i) q[t + i * 64] = f2b(vals[i] * inv);
}

// ---------------------------------------------------------------------------
// x = LayerNorm(x + y) * s + b  (fp32), also writes bf16 copy xb.
// ---------------------------------------------------------------------------
__global__ __launch_bounds__(256) void add_ln(
    float* __restrict__ x, unsigned short* __restrict__ xb,
    const float* __restrict__ y,
    const float* __restrict__ s, const float* __restrict__ b, int d)
{
    float* xr = x + (long)blockIdx.x * d;
    unsigned short* xbr = xb + (long)blockIdx.x * d;
    const float* yr = y + (long)blockIdx.x * d;
    const int t = threadIdx.x;
    float s1 = 0.f, s2 = 0.f;
    for (int i = t; i < d; i += 256) {
        float v = xr[i] + yr[i];
        s1 += v; s2 += v * v;
    }
    for (int off = 32; off; off >>= 1) { s1 += __shfl_down(s1, off); s2 += __shfl_down(s2, off); }
    __shared__ float r1[4], r2[4];
    int w = t >> 6;
    if ((t & 63) == 0) { r1[w] = s1; r2[w] = s2; }
    __syncthreads();
    if (t == 0) {
        float a = 0.f, c = 0.f;
        for (int i = 0; i < 4; ++i) { a += r1[i]; c += r2[i]; }
        r1[0] = a; r2[0] = c;
    }
    __syncthreads();
    float mean = r1[0] / d;
    float var = r2[0] / d - mean * mean;
    float rstd = rsqrtf(var + 1e-5f);
    for (int i = t; i < d; i += 256) {
        float v = (xr[i] + yr[i] - mean) * rstd * s[i] + b[i];
        xr[i] = v;
        xbr[i] = f2b(v);
    }
}

// ---------------------------------------------------------------------------
// init / concat (write fp32 + bf16 copies)
// ---------------------------------------------------------------------------
__global__ void initx_k(const float* __restrict__ src, float* __restrict__ dst,
                        unsigned short* __restrict__ dstb, int n)
{
    int i = blockIdx.x * blockDim.x + threadIdx.x;
    if (i < n) { float v = src[i]; dst[i] = v; dstb[i] = f2b(v); }
}

__global__ void concat_k(const float* __restrict__ te, const float* __restrict__ ve,
                         float* __restrict__ all, unsigned short* __restrict__ allb)
{
    int i = blockIdx.x * blockDim.x + threadIdx.x;
    if (i >= NTOK * 1536) return;
    int r = i / 1536, c = i % 1536;
    float v = (c < 768) ? te[r * 768 + c] : ve[r * 768 + (c - 768)];
    all[i] = v;
    allb[i] = f2b(v);
}

// ---------------------------------------------------------------------------
// head kernels (fp32)
// ---------------------------------------------------------------------------
__global__ __launch_bounds__(256) void head_ac(
    const float* __restrict__ all, const float* __restrict__ lin_w,
    const float* __restrict__ lin_b, float* __restrict__ a, float* __restrict__ c)
{
    const int i = blockIdx.x, t = threadIdx.x;
    const float* xr = all + (long)i * 1536;
    float s0 = 0.f, s1 = 0.f, s2 = 0.f, s3 = 0.f;
    for (int e = t; e < 1536; e += 256) {
        float v = xr[e];
        s0 += v * lin_w[e];
        s1 += v * lin_w[3072 + e];
        s2 += v * lin_w[1536 + e];
        s3 += v * lin_w[4608 + e];
    }
    for (int off = 32; off; off >>= 1) {
        s0 += __shfl_down(s0, off); s1 += __shfl_down(s1, off);
        s2 += __shfl_down(s2, off); s3 += __shfl_down(s3, off);
    }
    __shared__ float r[4][4];
    int w = t >> 6;
    if ((t & 63) == 0) { r[0][w] = s0; r[1][w] = s1; r[2][w] = s2; r[3][w] = s3; }
    __syncthreads();
    if (t == 0) {
        float t0 = 0.f, t1 = 0.f, t2 = 0.f, t3 = 0.f;
        for (int k = 0; k < 4; ++k) { t0 += r[0][k]; t1 += r[1][k]; t2 += r[2][k]; t3 += r[3][k]; }
        a[i * 2 + 0] = t0 + lin_b[0];
        a[i * 2 + 1] = t1 + lin_b[1];
        c[i * 2 + 0] = t2;
        c[i * 2 + 1] = t3;
    }
}

__global__ __launch_bounds__(384) void head_probs(
    const float* __restrict__ a, const float* __restrict__ c,
    const int* __restrict__ gt, float* __restrict__ probs,
    float* __restrict__ rowsum, float* __restrict__ rowcell)
{
    const int i = blockIdx.x, j = threadIdx.x;
    float l0 = a[i * 2 + 0] + c[j * 2 + 0];
    float l1 = a[i * 2 + 1] + c[j * 2 + 1];
    float m = fmaxf(l0, l1);
    float e0 = __expf(l0 - m), e1 = __expf(l1 - m);
    float inv = 1.f / (e0 + e1);
    float p0 = e0 * inv, p1 = e1 * inv;
    long base = ((long)i * NTOK + j) * 2;
    probs[base] = p0;
    probs[base + 1] = p1;
    float m2 = fmaxf(p0, p1);
    float z = m2 + __logf(__expf(p0 - m2) + __expf(p1 - m2));
    int g = gt[i * NTOK + j];
    float cell = z - (g ? p1 : p0);
    float cs = cell, ps = p1;
    for (int off = 32; off; off >>= 1) { cs += __shfl_down(cs, off); ps += __shfl_down(ps, off); }
    __shared__ float rc[6], rs[6];
    int w = j >> 6;
    if ((j & 63) == 0) { rc[w] = cs; rs[w] = ps; }
    __syncthreads();
    if (j == 0) {
        float csum = 0.f, psum = 0.f;
        for (int k = 0; k < 6; ++k) { csum += rc[k]; psum += rs[k]; }
        rowcell[i] = csum * (1.f / NTOK);
        rowsum[i] = psum;
    }
}

__global__ __launch_bounds__(64) void colsum_k(const float* __restrict__ probs,
                                               float* __restrict__ colsum)
{
    const int j = blockIdx.x, t = threadIdx.x;
    float s = 0.f;
    for (int i = t; i < NTOK; i += 64)
        s += probs[((long)i * NTOK + j) * 2 + 1];
    for (int off = 32; off; off >>= 1) s += __shfl_down(s, off);
    if (t == 0) colsum[j] = s;
}

__global__ __launch_bounds__(384) void finalize_k(
    const float* __restrict__ rowcell, const float* __restrict__ rowsum,
    const float* __restrict__ colsum, float* __restrict__ out)
{
    const int t = threadIdx.x;
    float cls = rowcell[t];
    float ee = (t < NTOK - 1) ? fabsf(rowsum[t] + colsum[t] - 1.f) : 0.f;
    for (int off = 32; off; off >>= 1) { cls += __shfl_down(cls, off); ee += __shfl_down(ee, off); }
    __shared__ float rc[6], re[6];
    int w = t >> 6;
    if ((t & 63) == 0) { rc[w] = cls; re[w] = ee; }
    __syncthreads();
    if (t == 0) {
        float a = 0.f, b = 0.f;
        for (int k = 0; k < 6; ++k) { a += rc[k]; b += re[k]; }
        out[NTOK * NTOK * 2 + 0] = a;
        out[NTOK * NTOK * 2 + 1] = b;
    }
}

// ---------------------------------------------------------------------------
// host-side encoder driver (fp32 weights consumed directly by gemm64 bf32
// staging path — no separate weight-conversion pass)
// ---------------------------------------------------------------------------
static void run_encoder(float* x, unsigned short* xb, int d,
                        const float* wq, const float* wo,
                        const float* w1, const float* w2,
                        const float* qkv_b, const float* out_b,
                        const float* ln1_s, const float* ln1_b,
                        const float* ff1_b, const float* ff2_b,
                        const float* ln2_s, const float* ln2_b,
                        unsigned short* qkvb, float* sc, unsigned short* attnb,
                        unsigned short* vtb, unsigned short* ob,
                        unsigned short* t1b, float* t2,
                        hipStream_t stream)
{
    const int dq = 3 * d;
    const int hd = d / HEADS;
    const float scale = 1.0f / sqrtf((float)hd);
    for (int l = 0; l < 2; ++l) {
        // qkv = x @ Wqkv^T + b (bf16; V block written transposed to vtb)
        gemm64<<<dim3(dq / 64, 6), 256, 0, stream>>>(
            xb, wq + (long)l * dq * d, qkv_b + l * dq, qkvb,
            d, d, d, dq, 0, 0, 0, 0, 1, vtb, 2 * d, 1);
        // scores = Q @ K^T (fp32), batched over heads
        gemm64<<<dim3(6, 6, HEADS), 256, 0, stream>>>(
            qkvb, qkvb + d, nullptr, sc,
            hd, dq, dq, NTOK, (long)hd, (long)hd, (long)NTOK * NTOK,
            0, 0, nullptr, 0, 0);
        softmax_rows<<<HEADS * NTOK, 64, 0, stream>>>(sc, attnb, scale);
        // o = attn @ V^T (bf16), batched over heads
        gemm64<<<dim3(hd / 64, 6, HEADS), 256, 0, stream>>>(
            attnb, vtb, nullptr, ob,
            NTOK, NTOK, NTOK, d, (long)NTOK * NTOK, (long)hd * NTOK, (long)hd,
            0, 1, nullptr, 0, 0);
        // out-proj (fp32) + LN
        gemm64<<<dim3(d / 64, 6), 256, 0, stream>>>(
            ob, wo + (long)l * d * d, out_b + l * d, t2,
            d, d, d, d, 0, 0, 0, 0, 0, nullptr, 0, 1);
        add_ln<<<NTOK, 256, 0, stream>>>(x, xb, t2, ln1_s + l * d, ln1_b + l * d, d);
        // ff1 (relu, bf16), ff2 (fp32) + LN
        gemm64<<<dim3(2048 / 64, 6), 256, 0, stream>>>(
            xb, w1 + (long)l * 2048 * d, ff1_b + l * 2048, t1b,
            d, d, d, 2048, 0, 0, 0, 1, 1, nullptr, 0, 1);
        gemm64<<<dim3(d / 64, 6), 256, 0, stream>>>(
            t1b, w2 + (long)l * d * 2048, ff2_b + l * d, t2,
            2048, 2048, 2048, d, 0, 0, 0, 0, 0, nullptr, 0, 1);
        add_ln<<<NTOK, 256, 0, stream>>>(x, xb, t2, ln2_s + l * d, ln2_b + l * d, d);
    }
}

extern "C" void kernel_launch(void* const* d_in, const int* in_sizes, int n_in,
                              void* d_out, int out_size, void* d_ws, size_t ws_size,
                              hipStream_t stream)
{
    const float* text_emb   = (const float*)d_in[0];
    const float* vision_emb = (const float*)d_in[1];
    const int*   gt         = (const int*)  d_in[2];
    const float* t_qkv_w = (const float*)d_in[3];
    const float* t_qkv_b = (const float*)d_in[4];
    const float* t_out_w = (const float*)d_in[5];
    const float* t_out_b = (const float*)d_in[6];
    const float* t_ln1_s = (const float*)d_in[7];
    const float* t_ln1_b = (const float*)d_in[8];
    const float* t_ff1_w = (const float*)d_in[9];
    const float* t_ff1_b = (const float*)d_in[10];
    const float* t_ff2_w = (const float*)d_in[11];
    const float* t_ff2_b = (const float*)d_in[12];
    const float* t_ln2_s = (const float*)d_in[13];
    const float* t_ln2_b = (const float*)d_in[14];
    const float* c_qkv_w = (const float*)d_in[15];
    const float* c_qkv_b = (const float*)d_in[16];
    const float* c_out_w = (const float*)d_in[17];
    const float* c_out_b = (const float*)d_in[18];
    const float* c_ln1_s = (const float*)d_in[19];
    const float* c_ln1_b = (const float*)d_in[20];
    const float* c_ff1_w = (const float*)d_in[21];
    const float* c_ff1_b = (const float*)d_in[22];
    const float* c_ff2_w = (const float*)d_in[23];
    const float* c_ff2_b = (const float*)d_in[24];
    const float* c_ln2_s = (const float*)d_in[25];
    const float* c_ln2_b = (const float*)d_in[26];
    const float* lin_w   = (const float*)d_in[27];
    const float* lin_b   = (const float*)d_in[28];
    float* out = (float*)d_out;

    // ---- workspace layout ----
    float* ws = (float*)d_ws;
    float* xt      = ws;                 // 384*768
    float* all     = xt + 294912;        // 384*1536
    float* t2      = all + 589824;       // 384*1536 (max)
    float* sc      = t2 + 589824;        // 4*384*384 fp32
    float* abuf    = sc + 589824;
    float* cbuf    = abuf + 768;
    float* rowsum  = cbuf + 768;
    float* rowcell = rowsum + 384;
    float* colsum  = rowcell + 384;      // fp32 total 2067072
    unsigned short* ub = (unsigned short*)(ws + 2067072);
    unsigned short* xtb   = ub;                  // 294912
    unsigned short* allb  = xtb + 294912;        // 589824
    unsigned short* qkvb  = allb + 589824;       // 384*4608
    unsigned short* attnb = qkvb + 1769472;      // 4*384*384
    unsigned short* vtb   = attnb + 589824;      // 1536*384 (max)
    unsigned short* ob    = vtb + 589824;        // 589824
    unsigned short* t1b   = ob + 589824;         // 384*2048

    // ---- text encoder (d = 768) ----
    initx_k<<<(294912 + 255) / 256, 256, 0, stream>>>(text_emb, xt, xtb, 294912);
    run_encoder(xt, xtb, 768,
                t_qkv_w, t_out_w, t_ff1_w, t_ff2_w,
                t_qkv_b, t_out_b, t_ln1_s, t_ln1_b,
                t_ff1_b, t_ff2_b, t_ln2_s, t_ln2_b,
                qkvb, sc, attnb, vtb, ob, t1b, t2, stream);

    // ---- concat -> combined encoder (d = 1536) ----
    concat_k<<<(589824 + 255) / 256, 256, 0, stream>>>(xt, vision_emb, all, allb);
    run_encoder(all, allb, 1536,
                c_qkv_w, c_out_w, c_ff1_w, c_ff2_w,
                c_qkv_b, c_out_b, c_ln1_s, c_ln1_b,
                c_ff1_b, c_ff2_b, c_ln2_s, c_ln2_b,
                qkvb, sc, attnb, vtb, ob, t1b, t2, stream);

    // ---- head ----
    head_ac<<<NTOK, 256, 0, stream>>>(all, lin_w, lin_b, abuf, cbuf);
    head_probs<<<NTOK, 384, 0, stream>>>(abuf, cbuf, gt, out, rowsum, rowcell);
    colsum_k<<<NTOK, 64, 0, stream>>>(out, colsum);
    finalize_k<<<1, 384, 0, stream>>>(rowcell, rowsum, colsum, out);
}

// Round 2
// 563.875 us; speedup vs baseline: 1.7061x; 1.7061x over previous
//
#include <hip/hip_runtime.h>
#include <hip/hip_bf16.h>
#include <math.h>

#define NTOK 384
#define HEADS 4

typedef __attribute__((ext_vector_type(8))) short bf16x8;
typedef __attribute__((ext_vector_type(4))) float f32x4;

__device__ __forceinline__ unsigned short f2b(float f) {
    union { float f; unsigned int u; } v; v.f = f;
    unsigned int r = (v.u + 0x7fff + ((v.u >> 16) & 1)) >> 16;  // RNE
    return (unsigned short)r;
}

// async 16B global -> LDS (wave-uniform LDS base; HW adds lane*16)
__device__ __forceinline__ void g2l16(const void* g, void* l) {
    __builtin_amdgcn_global_load_lds(
        (const __attribute__((address_space(1))) unsigned int*)g,
        (__attribute__((address_space(3))) unsigned int*)l, 16, 0, 0);
}

// ---------------------------------------------------------------------------
// 64x64-tile MFMA bf16 GEMM, batched over z. C = A@B^T + bias, opt relu,
// fp32/bf16 out, optional transposed-V epilogue for col0 >= dv2.
// Block 256 thr = 4 waves (2x2, 32x32 each). BK=64 (two 32-wide sub-steps),
// double-buffered LDS via global_load_lds; per buf: A0|A1|B0|B1 4KB regions.
// 64B LDS rows, 16B chunks rotated by (row>>1)&3.
// BK=64 halves the barrier count vs BK=32 — these GEMMs are latency-bound
// (1 block/CU, no TLP), so barrier-drain round-trips ARE the critical path.
// ---------------------------------------------------------------------------
__device__ __forceinline__ void stage64(
    const unsigned short* __restrict__ g, int row0, int k0, int ld,
    char* region, int wid, int lane)
{
    int c = wid * 64 + lane;                 // chunk 0..255
    int row = c >> 2, p = c & 3;
    int kc = (p - (row >> 1)) & 3;
    g2l16(g + (long)(row0 + row) * ld + k0 + kc * 8,
          region + (wid * 64) * 16);         // wave-uniform base
}

__global__ __launch_bounds__(256, 4) void gemm64(
    const unsigned short* __restrict__ A, const unsigned short* __restrict__ B,
    const float* __restrict__ bias, void* __restrict__ Cv,
    int K, int lda, int ldb, int ldc,
    long sA, long sB, long sC, int relu, int out_bf16,
    unsigned short* __restrict__ vt, int dv2)
{
    __shared__ char smem[2][16384];          // per buf: A0|A1|B0|B1 (4KB each)
    A += (long)blockIdx.z * sA;
    B += (long)blockIdx.z * sB;
    const int t = threadIdx.x, lane = t & 63, wid = t >> 6;
    const int wm = wid >> 1, wn = wid & 1;
    const int r16 = lane & 15, quad = lane >> 4;
    const int row0 = blockIdx.y * 64, col0 = blockIdx.x * 64;

    f32x4 acc[2][2] = {};

    stage64(A, row0,  0, lda, smem[0],         wid, lane);
    stage64(A, row0, 32, lda, smem[0] +  4096, wid, lane);
    stage64(B, col0,  0, ldb, smem[0] +  8192, wid, lane);
    stage64(B, col0, 32, ldb, smem[0] + 12288, wid, lane);
    int buf = 0;

    for (int k0 = 0; k0 < K; k0 += 64) {
        __syncthreads();
        if (k0 + 64 < K) {
            stage64(A, row0, k0 + 64, lda, smem[buf ^ 1],         wid, lane);
            stage64(A, row0, k0 + 96, lda, smem[buf ^ 1] +  4096, wid, lane);
            stage64(B, col0, k0 + 64, ldb, smem[buf ^ 1] +  8192, wid, lane);
            stage64(B, col0, k0 + 96, ldb, smem[buf ^ 1] + 12288, wid, lane);
        }
        const char* cb = smem[buf];
        #pragma unroll
        for (int h = 0; h < 2; ++h) {
            bf16x8 af[2], bfv[2];
            #pragma unroll
            for (int rt = 0; rt < 2; ++rt) {
                int row = wm * 32 + rt * 16 + r16;
                int p = (quad + (row >> 1)) & 3;
                af[rt] = *reinterpret_cast<const bf16x8*>(
                    cb + h * 4096 + row * 64 + p * 16);
            }
            #pragma unroll
            for (int ct = 0; ct < 2; ++ct) {
                int col = wn * 32 + ct * 16 + r16;
                int p = (quad + (col >> 1)) & 3;
                bfv[ct] = *reinterpret_cast<const bf16x8*>(
                    cb + 8192 + h * 4096 + col * 64 + p * 16);
            }
            #pragma unroll
            for (int rt = 0; rt < 2; ++rt)
                #pragma unroll
                for (int ct = 0; ct < 2; ++ct)
                    acc[rt][ct] = __builtin_amdgcn_mfma_f32_16x16x32_bf16(
                        af[rt], bfv[ct], acc[rt][ct], 0, 0, 0);
        }
        buf ^= 1;
    }

    float* Cf = (float*)Cv;
    unsigned short* Cb = (unsigned short*)Cv;
    const long zoff = (long)blockIdx.z * sC;
    const int vwrite = (vt != nullptr) && (col0 >= dv2);
    #pragma unroll
    for (int rt = 0; rt < 2; ++rt) {
        #pragma unroll
        for (int ct = 0; ct < 2; ++ct) {
            f32x4 v = acc[rt][ct];
            int col = col0 + wn * 32 + ct * 16 + r16;
            float bi = bias ? bias[col] : 0.f;
            #pragma unroll
            for (int i = 0; i < 4; ++i) {
                v[i] += bi;
                if (relu) v[i] = fmaxf(v[i], 0.f);
            }
            int rbase = row0 + wm * 32 + rt * 16 + quad * 4;
            if (vwrite) {
                ushort4 p;
                p.x = f2b(v[0]); p.y = f2b(v[1]); p.z = f2b(v[2]); p.w = f2b(v[3]);
                *reinterpret_cast<ushort4*>(vt + (long)(col - dv2) * NTOK + rbase) = p;
            } else if (out_bf16) {
                #pragma unroll
                for (int i = 0; i < 4; ++i)
                    Cb[zoff + (long)(rbase + i) * ldc + col] = f2b(v[i]);
            } else {
                #pragma unroll
                for (int i = 0; i < 4; ++i)
                    Cf[zoff + (long)(rbase + i) * ldc + col] = v[i];
            }
        }
    }
}

// ---------------------------------------------------------------------------
// Fused fp32 -> bf16 conversion of all 8 weight tensors. 32B read / 16B
// write per thread.
// ---------------------------------------------------------------------------
#define WO0 0u
#define WO1 3538944u
#define WO2 4718592u
#define WO3 7864320u
#define WO4 11010048u
#define WO5 25165824u
#define WO6 29884416u
#define WO7 36175872u
#define WTOT 42467328u

__global__ __launch_bounds__(256) void convert_weights(
    const float* __restrict__ s0, const float* __restrict__ s1,
    const float* __restrict__ s2, const float* __restrict__ s3,
    const float* __restrict__ s4, const float* __restrict__ s5,
    const float* __restrict__ s6, const float* __restrict__ s7,
    unsigned short* __restrict__ dst)
{
    unsigned int e = (blockIdx.x * 256u + threadIdx.x) * 8u;
    if (e >= WTOT) return;
    const float* src; unsigned int local;
    if      (e < WO1) { src = s0; local = e - WO0; }
    else if (e < WO2) { src = s1; local = e - WO1; }
    else if (e < WO3) { src = s2; local = e - WO2; }
    else if (e < WO4) { src = s3; local = e - WO3; }
    else if (e < WO5) { src = s4; local = e - WO4; }
    else if (e < WO6) { src = s5; local = e - WO5; }
    else if (e < WO7) { src = s6; local = e - WO6; }
    else              { src = s7; local = e - WO7; }
    float4 v0 = *reinterpret_cast<const float4*>(src + local);
    float4 v1 = *reinterpret_cast<const float4*>(src + local + 4);
    uint4 o;
    o.x = (unsigned)f2b(v0.x) | ((unsigned)f2b(v0.y) << 16);
    o.y = (unsigned)f2b(v0.z) | ((unsigned)f2b(v0.w) << 16);
    o.z = (unsigned)f2b(v1.x) | ((unsigned)f2b(v1.y) << 16);
    o.w = (unsigned)f2b(v1.z) | ((unsigned)f2b(v1.w) << 16);
    *reinterpret_cast<uint4*>(dst + e) = o;
}

// ---------------------------------------------------------------------------
// Softmax over rows of length 384 (one wave per row); fp32 in, bf16 out.
// ---------------------------------------------------------------------------
__global__ __launch_bounds__(64) void softmax_rows(
    const float* __restrict__ S, unsigned short* __restrict__ P, float scale)
{
    const float* p = S + (long)blockIdx.x * NTOK;
    unsigned short* q = P + (long)blockIdx.x * NTOK;
    const int t = threadIdx.x;
    float vals[6];
    float vmax = -1e30f;
    #pragma unroll
    for (int i = 0; i < 6; ++i) {
        vals[i] = p[t + i * 64] * scale;
        vmax = fmaxf(vmax, vals[i]);
    }
    for (int off = 32; off; off >>= 1) vmax = fmaxf(vmax, __shfl_down(vmax, off));
    vmax = __shfl(vmax, 0);
    float sum = 0.f;
    #pragma unroll
    for (int i = 0; i < 6; ++i) { vals[i] = __expf(vals[i] - vmax); sum += vals[i]; }
    for (int off = 32; off; off >>= 1) sum += __shfl_down(sum, off);
    sum = __shfl(sum, 0);
    float inv = 1.f / sum;
    #pragma unroll
    for (int i = 0; i < 6; ++i) q[t + i * 64] = f2b(vals[i] * inv);
}

// ---------------------------------------------------------------------------
// x = LayerNorm(x + y) * s + b  (fp32), also writes bf16 copy xb.
// ---------------------------------------------------------------------------
__global__ __launch_bounds__(256) void add_ln(
    float* __restrict__ x, unsigned short* __restrict__ xb,
    const float* __restrict__ y,
    const float* __restrict__ s, const float* __restrict__ b, int d)
{
    float* xr = x + (long)blockIdx.x * d;
    unsigned short* xbr = xb + (long)blockIdx.x * d;
    const float* yr = y + (long)blockIdx.x * d;
    const int t = threadIdx.x;
    float s1 = 0.f, s2 = 0.f;
    for (int i = t; i < d; i += 256) {
        float v = xr[i] + yr[i];
        s1 += v; s2 += v * v;
    }
    for (int off = 32; off; off >>= 1) { s1 += __shfl_down(s1, off); s2 += __shfl_down(s2, off); }
    __shared__ float r1[4], r2[4];
    int w = t >> 6;
    if ((t & 63) == 0) { r1[w] = s1; r2[w] = s2; }
    __syncthreads();
    if (t == 0) {
        float a = 0.f, c = 0.f;
        for (int i = 0; i < 4; ++i) { a += r1[i]; c += r2[i]; }
        r1[0] = a; r2[0] = c;
    }
    __syncthreads();
    float mean = r1[0] / d;
    float var = r2[0] / d - mean * mean;
    float rstd = rsqrtf(var + 1e-5f);
    for (int i = t; i < d; i += 256) {
        float v = (xr[i] + yr[i] - mean) * rstd * s[i] + b[i];
        xr[i] = v;
        xbr[i] = f2b(v);
    }
}

// ---------------------------------------------------------------------------
// init / concat (write fp32 + bf16 copies)
// ---------------------------------------------------------------------------
__global__ void initx_k(const float* __restrict__ src, float* __restrict__ dst,
                        unsigned short* __restrict__ dstb, int n)
{
    int i = blockIdx.x * blockDim.x + threadIdx.x;
    if (i < n) { float v = src[i]; dst[i] = v; dstb[i] = f2b(v); }
}

__global__ void concat_k(const float* __restrict__ te, const float* __restrict__ ve,
                         float* __restrict__ all, unsigned short* __restrict__ allb)
{
    int i = blockIdx.x * blockDim.x + threadIdx.x;
    if (i >= NTOK * 1536) return;
    int r = i / 1536, c = i % 1536;
    float v = (c < 768) ? te[r * 768 + c] : ve[r * 768 + (c - 768)];
    all[i] = v;
    allb[i] = f2b(v);
}

// ---------------------------------------------------------------------------
// head kernels (fp32)
// ---------------------------------------------------------------------------
__global__ __launch_bounds__(256) void head_ac(
    const float* __restrict__ all, const float* __restrict__ lin_w,
    const float* __restrict__ lin_b, float* __restrict__ a, float* __restrict__ c)
{
    const int i = blockIdx.x, t = threadIdx.x;
    const float* xr = all + (long)i * 1536;
    float s0 = 0.f, s1 = 0.f, s2 = 0.f, s3 = 0.f;
    for (int e = t; e < 1536; e += 256) {
        float v = xr[e];
        s0 += v * lin_w[e];
        s1 += v * lin_w[3072 + e];
        s2 += v * lin_w[1536 + e];
        s3 += v * lin_w[4608 + e];
    }
    for (int off = 32; off; off >>= 1) {
        s0 += __shfl_down(s0, off); s1 += __shfl_down(s1, off);
        s2 += __shfl_down(s2, off); s3 += __shfl_down(s3, off);
    }
    __shared__ float r[4][4];
    int w = t >> 6;
    if ((t & 63) == 0) { r[0][w] = s0; r[1][w] = s1; r[2][w] = s2; r[3][w] = s3; }
    __syncthreads();
    if (t == 0) {
        float t0 = 0.f, t1 = 0.f, t2 = 0.f, t3 = 0.f;
        for (int k = 0; k < 4; ++k) { t0 += r[0][k]; t1 += r[1][k]; t2 += r[2][k]; t3 += r[3][k]; }
        a[i * 2 + 0] = t0 + lin_b[0];
        a[i * 2 + 1] = t1 + lin_b[1];
        c[i * 2 + 0] = t2;
        c[i * 2 + 1] = t3;
    }
}

__global__ __launch_bounds__(384) void head_probs(
    const float* __restrict__ a, const float* __restrict__ c,
    const int* __restrict__ gt, float* __restrict__ probs,
    float* __restrict__ rowsum, float* __restrict__ rowcell)
{
    const int i = blockIdx.x, j = threadIdx.x;
    float l0 = a[i * 2 + 0] + c[j * 2 + 0];
    float l1 = a[i * 2 + 1] + c[j * 2 + 1];
    float m = fmaxf(l0, l1);
    float e0 = __expf(l0 - m), e1 = __expf(l1 - m);
    float inv = 1.f / (e0 + e1);
    float p0 = e0 * inv, p1 = e1 * inv;
    long base = ((long)i * NTOK + j) * 2;
    probs[base] = p0;
    probs[base + 1] = p1;
    float m2 = fmaxf(p0, p1);
    float z = m2 + __logf(__expf(p0 - m2) + __expf(p1 - m2));
    int g = gt[i * NTOK + j];
    float cell = z - (g ? p1 : p0);
    float cs = cell, ps = p1;
    for (int off = 32; off; off >>= 1) { cs += __shfl_down(cs, off); ps += __shfl_down(ps, off); }
    __shared__ float rc[6], rs[6];
    int w = j >> 6;
    if ((j & 63) == 0) { rc[w] = cs; rs[w] = ps; }
    __syncthreads();
    if (j == 0) {
        float csum = 0.f, psum = 0.f;
        for (int k = 0; k < 6; ++k) { csum += rc[k]; psum += rs[k]; }
        rowcell[i] = csum * (1.f / NTOK);
        rowsum[i] = psum;
    }
}

__global__ __launch_bounds__(64) void colsum_k(const float* __restrict__ probs,
                                               float* __restrict__ colsum)
{
    const int j = blockIdx.x, t = threadIdx.x;
    float s = 0.f;
    for (int i = t; i < NTOK; i += 64)
        s += probs[((long)i * NTOK + j) * 2 + 1];
    for (int off = 32; off; off >>= 1) s += __shfl_down(s, off);
    if (t == 0) colsum[j] = s;
}

__global__ __launch_bounds__(384) void finalize_k(
    const float* __restrict__ rowcell, const float* __restrict__ rowsum,
    const float* __restrict__ colsum, float* __restrict__ out)
{
    const int t = threadIdx.x;
    float cls = rowcell[t];
    float ee = (t < NTOK - 1) ? fabsf(rowsum[t] + colsum[t] - 1.f) : 0.f;
    for (int off = 32; off; off >>= 1) { cls += __shfl_down(cls, off); ee += __shfl_down(ee, off); }
    __shared__ float rc[6], re[6];
    int w = t >> 6;
    if ((t & 63) == 0) { rc[w] = cls; re[w] = ee; }
    __syncthreads();
    if (t == 0) {
        float a = 0.f, b = 0.f;
        for (int k = 0; k < 6; ++k) { a += rc[k]; b += re[k]; }
        out[NTOK * NTOK * 2 + 0] = a;
        out[NTOK * NTOK * 2 + 1] = b;
    }
}

// ---------------------------------------------------------------------------
// host-side encoder driver (bf16 weights, 64-tile staged gemms)
// ---------------------------------------------------------------------------
static void run_encoder(float* x, unsigned short* xb, int d,
                        const unsigned short* wq, const unsigned short* wo,
                        const unsigned short* w1, const unsigned short* w2,
                        const float* qkv_b, const float* out_b,
                        const float* ln1_s, const float* ln1_b,
                        const float* ff1_b, const float* ff2_b,
                        const float* ln2_s, const float* ln2_b,
                        unsigned short* qkvb, float* sc, unsigned short* attnb,
                        unsigned short* vtb, unsigned short* ob,
                        unsigned short* t1b, float* t2,
                        hipStream_t stream)
{
    const int dq = 3 * d;
    const int hd = d / HEADS;
    const float scale = 1.0f / sqrtf((float)hd);
    for (int l = 0; l < 2; ++l) {
        // qkv = x @ Wqkv^T + b (bf16; V block written transposed to vtb)
        gemm64<<<dim3(dq / 64, 6), 256, 0, stream>>>(
            xb, wq + (long)l * dq * d, qkv_b + l * dq, qkvb,
            d, d, d, dq, 0, 0, 0, 0, 1, vtb, 2 * d);
        // scores = Q @ K^T (fp32), batched over heads
        gemm64<<<dim3(6, 6, HEADS), 256, 0, stream>>>(
            qkvb, qkvb + d, nullptr, sc,
            hd, dq, dq, NTOK, (long)hd, (long)hd, (long)NTOK * NTOK,
            0, 0, nullptr, 0);
        softmax_rows<<<HEADS * NTOK, 64, 0, stream>>>(sc, attnb, scale);
        // o = attn @ V^T (bf16), batched over heads
        gemm64<<<dim3(hd / 64, 6, HEADS), 256, 0, stream>>>(
            attnb, vtb, nullptr, ob,
            NTOK, NTOK, NTOK, d, (long)NTOK * NTOK, (long)hd * NTOK, (long)hd,
            0, 1, nullptr, 0);
        // out-proj (fp32) + LN
        gemm64<<<dim3(d / 64, 6), 256, 0, stream>>>(
            ob, wo + (long)l * d * d, out_b + l * d, t2,
            d, d, d, d, 0, 0, 0, 0, 0, nullptr, 0);
        add_ln<<<NTOK, 256, 0, stream>>>(x, xb, t2, ln1_s + l * d, ln1_b + l * d, d);
        // ff1 (relu, bf16), ff2 (fp32) + LN
        gemm64<<<dim3(2048 / 64, 6), 256, 0, stream>>>(
            xb, w1 + (long)l * 2048 * d, ff1_b + l * 2048, t1b,
            d, d, d, 2048, 0, 0, 0, 1, 1, nullptr, 0);
        gemm64<<<dim3(d / 64, 6), 256, 0, stream>>>(
            t1b, w2 + (long)l * d * 2048, ff2_b + l * d, t2,
            2048, 2048, 2048, d, 0, 0, 0, 0, 0, nullptr, 0);
        add_ln<<<NTOK, 256, 0, stream>>>(x, xb, t2, ln2_s + l * d, ln2_b + l * d, d);
    }
}

extern "C" void kernel_launch(void* const* d_in, const int* in_sizes, int n_in,
                              void* d_out, int out_size, void* d_ws, size_t ws_size,
                              hipStream_t stream)
{
    const float* text_emb   = (const float*)d_in[0];
    const float* vision_emb = (const float*)d_in[1];
    const int*   gt         = (const int*)  d_in[2];
    const float* t_qkv_w = (const float*)d_in[3];
    const float* t_qkv_b = (const float*)d_in[4];
    const float* t_out_w = (const float*)d_in[5];
    const float* t_out_b = (const float*)d_in[6];
    const float* t_ln1_s = (const float*)d_in[7];
    const float* t_ln1_b = (const float*)d_in[8];
    const float* t_ff1_w = (const float*)d_in[9];
    const float* t_ff1_b = (const float*)d_in[10];
    const float* t_ff2_w = (const float*)d_in[11];
    const float* t_ff2_b = (const float*)d_in[12];
    const float* t_ln2_s = (const float*)d_in[13];
    const float* t_ln2_b = (const float*)d_in[14];
    const float* c_qkv_w = (const float*)d_in[15];
    const float* c_qkv_b = (const float*)d_in[16];
    const float* c_out_w = (const float*)d_in[17];
    const float* c_out_b = (const float*)d_in[18];
    const float* c_ln1_s = (const float*)d_in[19];
    const float* c_ln1_b = (const float*)d_in[20];
    const float* c_ff1_w = (const float*)d_in[21];
    const float* c_ff1_b = (const float*)d_in[22];
    const float* c_ff2_w = (const float*)d_in[23];
    const float* c_ff2_b = (const float*)d_in[24];
    const float* c_ln2_s = (const float*)d_in[25];
    const float* c_ln2_b = (const float*)d_in[26];
    const float* lin_w   = (const float*)d_in[27];
    const float* lin_b   = (const float*)d_in[28];
    float* out = (float*)d_out;

    // ---- workspace layout ----
    float* ws = (float*)d_ws;
    float* xt      = ws;                 // 384*768
    float* all     = xt + 294912;        // 384*1536
    float* t2      = all + 589824;       // 384*1536 (max)
    float* sc      = t2 + 589824;        // 4*384*384 fp32
    float* abuf    = sc + 589824;
    float* cbuf    = abuf + 768;
    float* rowsum  = cbuf + 768;
    float* rowcell = rowsum + 384;
    float* colsum  = rowcell + 384;      // fp32 total 2067072
    unsigned short* ub = (unsigned short*)(ws + 2067072);
    unsigned short* xtb   = ub;                  // 294912
    unsigned short* allb  = xtb + 294912;        // 589824
    unsigned short* qkvb  = allb + 589824;       // 384*4608
    unsigned short* attnb = qkvb + 1769472;      // 4*384*384
    unsigned short* vtb   = attnb + 589824;      // 1536*384 (max)
    unsigned short* ob    = vtb + 589824;        // 589824
    unsigned short* t1b   = ob + 589824;         // 384*2048
    unsigned short* wb    = t1b + 786432;        // 42467328 bf16 weights

    // ---- weight conversion (one fused launch) ----
    convert_weights<<<(WTOT / 8 + 255) / 256, 256, 0, stream>>>(
        t_qkv_w, t_out_w, t_ff1_w, t_ff2_w,
        c_qkv_w, c_out_w, c_ff1_w, c_ff2_w, wb);

    // ---- text encoder (d = 768) ----
    initx_k<<<(294912 + 255) / 256, 256, 0, stream>>>(text_emb, xt, xtb, 294912);
    run_encoder(xt, xtb, 768,
                wb + WO0, wb + WO1, wb + WO2, wb + WO3,
                t_qkv_b, t_out_b, t_ln1_s, t_ln1_b,
                t_ff1_b, t_ff2_b, t_ln2_s, t_ln2_b,
                qkvb, sc, attnb, vtb, ob, t1b, t2, stream);

    // ---- concat -> combined encoder (d = 1536) ----
    concat_k<<<(589824 + 255) / 256, 256, 0, stream>>>(xt, vision_emb, all, allb);
    run_encoder(all, allb, 1536,
                wb + WO4, wb + WO5, wb + WO6, wb + WO7,
                c_qkv_b, c_out_b, c_ln1_s, c_ln1_b,
                c_ff1_b, c_ff2_b, c_ln2_s, c_ln2_b,
                qkvb, sc, attnb, vtb, ob, t1b, t2, stream);

    // ---- head ----
    head_ac<<<NTOK, 256, 0, stream>>>(all, lin_w, lin_b, abuf, cbuf);
    head_probs<<<NTOK, 384, 0, stream>>>(abuf, cbuf, gt, out, rowsum, rowcell);
    colsum_k<<<NTOK, 64, 0, stream>>>(out, colsum);
    finalize_k<<<1, 384, 0, stream>>>(rowcell, rowsum, colsum, out);
}

// Round 4
// 501.815 us; speedup vs baseline: 1.9170x; 1.1237x over previous
//
#include <hip/hip_runtime.h>
#include <hip/hip_bf16.h>
#include <math.h>

#define NTOK 384
#define HEADS 4

typedef __attribute__((ext_vector_type(8))) short bf16x8;
typedef __attribute__((ext_vector_type(4))) float f32x4;

__device__ __forceinline__ unsigned short f2b(float f) {
    union { float f; unsigned int u; } v; v.f = f;
    unsigned int r = (v.u + 0x7fff + ((v.u >> 16) & 1)) >> 16;  // RNE
    return (unsigned short)r;
}

// async 16B global -> LDS (wave-uniform LDS base; HW adds lane*16)
__device__ __forceinline__ void g2l16(const void* g, void* l) {
    __builtin_amdgcn_global_load_lds(
        (const __attribute__((address_space(1))) unsigned int*)g,
        (__attribute__((address_space(3))) unsigned int*)l, 16, 0, 0);
}

// ---------------------------------------------------------------------------
// 64x64-tile MFMA bf16 GEMM, batched over z. C = A@B^T + bias, opt relu,
// fp32/bf16 out, optional transposed-V epilogue for col0 >= dv2.
// Block 256 thr = 4 waves (2x2, 32x32 each). BK=64, TRIPLE-buffered LDS with
// a depth-2 counted-vmcnt pipeline: raw s_barrier + s_waitcnt vmcnt(4) keeps
// the next tile's global_load_lds in flight ACROSS the barrier (the
// __syncthreads() version drains vmcnt(0) and serializes the full load
// latency every K-iter — these GEMMs run at 1-2 blocks/CU, nothing else
// hides it). 4 loads/tile; waits are tile-granular.
// Safety audit: tile kt lives in smem[kt%3]; stage(kt+2) overwrites
// smem[(kt-1)%3] whose last reader finished before barrier(kt); vmcnt at
// the wait point counts exactly tiles kt,kt+1 (8 loads) -> vmcnt(4).
// ---------------------------------------------------------------------------
__device__ __forceinline__ void stage64(
    const unsigned short* __restrict__ g, int row0, int k0, int ld,
    char* region, int wid, int lane)
{
    int c = wid * 64 + lane;                 // chunk 0..255
    int row = c >> 2, p = c & 3;
    int kc = (p - (row >> 1)) & 3;
    g2l16(g + (long)(row0 + row) * ld + k0 + kc * 8,
          region + (wid * 64) * 16);         // wave-uniform base
}

__device__ __forceinline__ void stage_tile(
    const unsigned short* __restrict__ A, const unsigned short* __restrict__ B,
    int row0, int col0, int k0, int lda, int ldb,
    char* buf, int wid, int lane)
{
    stage64(A, row0, k0,      lda, buf,         wid, lane);
    stage64(A, row0, k0 + 32, lda, buf +  4096, wid, lane);
    stage64(B, col0, k0,      ldb, buf +  8192, wid, lane);
    stage64(B, col0, k0 + 32, ldb, buf + 12288, wid, lane);
    __builtin_amdgcn_sched_barrier(0);       // keep the 4 loads contiguous
}

__global__ __launch_bounds__(256, 3) void gemm64(
    const unsigned short* __restrict__ A, const unsigned short* __restrict__ B,
    const float* __restrict__ bias, void* __restrict__ Cv,
    int K, int lda, int ldb, int ldc,
    long sA, long sB, long sC, int relu, int out_bf16,
    unsigned short* __restrict__ vt, int dv2)
{
    __shared__ char smem[3][16384];          // per buf: A0|A1|B0|B1 (4KB each)
    A += (long)blockIdx.z * sA;
    B += (long)blockIdx.z * sB;
    const int t = threadIdx.x, lane = t & 63, wid = t >> 6;
    const int wm = wid >> 1, wn = wid & 1;
    const int r16 = lane & 15, quad = lane >> 4;
    const int row0 = blockIdx.y * 64, col0 = blockIdx.x * 64;

    f32x4 acc[2][2] = {};
    const int NT = K >> 6;                   // K is a multiple of 64 here

    stage_tile(A, B, row0, col0, 0, lda, ldb, smem[0], wid, lane);
    if (NT > 1)
        stage_tile(A, B, row0, col0, 64, lda, ldb, smem[1], wid, lane);

    int cur = 0, sb = 2;
    for (int kt = 0; kt < NT; ++kt) {
        // wait for tile kt (oldest 4 loads); keep tile kt+1's 4 in flight
        if (kt + 1 < NT) asm volatile("s_waitcnt vmcnt(4)" ::: "memory");
        else             asm volatile("s_waitcnt vmcnt(0) lgkmcnt(0)" ::: "memory");
        __builtin_amdgcn_s_barrier();
        if (kt + 2 < NT) {
            stage_tile(A, B, row0, col0, (kt + 2) * 64, lda, ldb,
                       smem[sb], wid, lane);
            sb = (sb == 2) ? 0 : sb + 1;
        }
        const char* cb = smem[cur];
        cur = (cur == 2) ? 0 : cur + 1;
        #pragma unroll
        for (int h = 0; h < 2; ++h) {
            bf16x8 af[2], bfv[2];
            #pragma unroll
            for (int rt = 0; rt < 2; ++rt) {
                int row = wm * 32 + rt * 16 + r16;
                int p = (quad + (row >> 1)) & 3;
                af[rt] = *reinterpret_cast<const bf16x8*>(
                    cb + h * 4096 + row * 64 + p * 16);
            }
            #pragma unroll
            for (int ct = 0; ct < 2; ++ct) {
                int col = wn * 32 + ct * 16 + r16;
                int p = (quad + (col >> 1)) & 3;
                bfv[ct] = *reinterpret_cast<const bf16x8*>(
                    cb + 8192 + h * 4096 + col * 64 + p * 16);
            }
            #pragma unroll
            for (int rt = 0; rt < 2; ++rt)
                #pragma unroll
                for (int ct = 0; ct < 2; ++ct)
                    acc[rt][ct] = __builtin_amdgcn_mfma_f32_16x16x32_bf16(
                        af[rt], bfv[ct], acc[rt][ct], 0, 0, 0);
        }
    }

    float* Cf = (float*)Cv;
    unsigned short* Cb = (unsigned short*)Cv;
    const long zoff = (long)blockIdx.z * sC;
    const int vwrite = (vt != nullptr) && (col0 >= dv2);
    #pragma unroll
    for (int rt = 0; rt < 2; ++rt) {
        #pragma unroll
        for (int ct = 0; ct < 2; ++ct) {
            f32x4 v = acc[rt][ct];
            int col = col0 + wn * 32 + ct * 16 + r16;
            float bi = bias ? bias[col] : 0.f;
            #pragma unroll
            for (int i = 0; i < 4; ++i) {
                v[i] += bi;
                if (relu) v[i] = fmaxf(v[i], 0.f);
            }
            int rbase = row0 + wm * 32 + rt * 16 + quad * 4;
            if (vwrite) {
                ushort4 p;
                p.x = f2b(v[0]); p.y = f2b(v[1]); p.z = f2b(v[2]); p.w = f2b(v[3]);
                *reinterpret_cast<ushort4*>(vt + (long)(col - dv2) * NTOK + rbase) = p;
            } else if (out_bf16) {
                #pragma unroll
                for (int i = 0; i < 4; ++i)
                    Cb[zoff + (long)(rbase + i) * ldc + col] = f2b(v[i]);
            } else {
                #pragma unroll
                for (int i = 0; i < 4; ++i)
                    Cf[zoff + (long)(rbase + i) * ldc + col] = v[i];
            }
        }
    }
}

// ---------------------------------------------------------------------------
// Fused fp32 -> bf16 conversion of all 8 weight tensors. 32B read / 16B
// write per thread.
// ---------------------------------------------------------------------------
#define WO0 0u
#define WO1 3538944u
#define WO2 4718592u
#define WO3 7864320u
#define WO4 11010048u
#define WO5 25165824u
#define WO6 29884416u
#define WO7 36175872u
#define WTOT 42467328u

__global__ __launch_bounds__(256) void convert_weights(
    const float* __restrict__ s0, const float* __restrict__ s1,
    const float* __restrict__ s2, const float* __restrict__ s3,
    const float* __restrict__ s4, const float* __restrict__ s5,
    const float* __restrict__ s6, const float* __restrict__ s7,
    unsigned short* __restrict__ dst)
{
    unsigned int e = (blockIdx.x * 256u + threadIdx.x) * 8u;
    if (e >= WTOT) return;
    const float* src; unsigned int local;
    if      (e < WO1) { src = s0; local = e - WO0; }
    else if (e < WO2) { src = s1; local = e - WO1; }
    else if (e < WO3) { src = s2; local = e - WO2; }
    else if (e < WO4) { src = s3; local = e - WO3; }
    else if (e < WO5) { src = s4; local = e - WO4; }
    else if (e < WO6) { src = s5; local = e - WO5; }
    else if (e < WO7) { src = s6; local = e - WO6; }
    else              { src = s7; local = e - WO7; }
    float4 v0 = *reinterpret_cast<const float4*>(src + local);
    float4 v1 = *reinterpret_cast<const float4*>(src + local + 4);
    uint4 o;
    o.x = (unsigned)f2b(v0.x) | ((unsigned)f2b(v0.y) << 16);
    o.y = (unsigned)f2b(v0.z) | ((unsigned)f2b(v0.w) << 16);
    o.z = (unsigned)f2b(v1.x) | ((unsigned)f2b(v1.y) << 16);
    o.w = (unsigned)f2b(v1.z) | ((unsigned)f2b(v1.w) << 16);
    *reinterpret_cast<uint4*>(dst + e) = o;
}

// ---------------------------------------------------------------------------
// Softmax over rows of length 384 (one wave per row); fp32 in, bf16 out.
// ---------------------------------------------------------------------------
__global__ __launch_bounds__(64) void softmax_rows(
    const float* __restrict__ S, unsigned short* __restrict__ P, float scale)
{
    const float* p = S + (long)blockIdx.x * NTOK;
    unsigned short* q = P + (long)blockIdx.x * NTOK;
    const int t = threadIdx.x;
    float vals[6];
    float vmax = -1e30f;
    #pragma unroll
    for (int i = 0; i < 6; ++i) {
        vals[i] = p[t + i * 64] * scale;
        vmax = fmaxf(vmax, vals[i]);
    }
    for (int off = 32; off; off >>= 1) vmax = fmaxf(vmax, __shfl_down(vmax, off));
    vmax = __shfl(vmax, 0);
    float sum = 0.f;
    #pragma unroll
    for (int i = 0; i < 6; ++i) { vals[i] = __expf(vals[i] - vmax); sum += vals[i]; }
    for (int off = 32; off; off >>= 1) sum += __shfl_down(sum, off);
    sum = __shfl(sum, 0);
    float inv = 1.f / sum;
    #pragma unroll
    for (int i = 0; i < 6; ++i) q[t + i * 64] = f2b(vals[i] * inv);
}

// ---------------------------------------------------------------------------
// x = LayerNorm(x + y) * s + b  (fp32), also writes bf16 copy xb.
// ---------------------------------------------------------------------------
__global__ __launch_bounds__(256) void add_ln(
    float* __restrict__ x, unsigned short* __restrict__ xb,
    const float* __restrict__ y,
    const float* __restrict__ s, const float* __restrict__ b, int d)
{
    float* xr = x + (long)blockIdx.x * d;
    unsigned short* xbr = xb + (long)blockIdx.x * d;
    const float* yr = y + (long)blockIdx.x * d;
    const int t = threadIdx.x;
    float s1 = 0.f, s2 = 0.f;
    for (int i = t; i < d; i += 256) {
        float v = xr[i] + yr[i];
        s1 += v; s2 += v * v;
    }
    for (int off = 32; off; off >>= 1) { s1 += __shfl_down(s1, off); s2 += __shfl_down(s2, off); }
    __shared__ float r1[4], r2[4];
    int w = t >> 6;
    if ((t & 63) == 0) { r1[w] = s1; r2[w] = s2; }
    __syncthreads();
    if (t == 0) {
        float a = 0.f, c = 0.f;
        for (int i = 0; i < 4; ++i) { a += r1[i]; c += r2[i]; }
        r1[0] = a; r2[0] = c;
    }
    __syncthreads();
    float mean = r1[0] / d;
    float var = r2[0] / d - mean * mean;
    float rstd = rsqrtf(var + 1e-5f);
    for (int i = t; i < d; i += 256) {
        float v = (xr[i] + yr[i] - mean) * rstd * s[i] + b[i];
        xr[i] = v;
        xbr[i] = f2b(v);
    }
}

// ---------------------------------------------------------------------------
// init / concat (write fp32 + bf16 copies)
// ---------------------------------------------------------------------------
__global__ void initx_k(const float* __restrict__ src, float* __restrict__ dst,
                        unsigned short* __restrict__ dstb, int n)
{
    int i = blockIdx.x * blockDim.x + threadIdx.x;
    if (i < n) { float v = src[i]; dst[i] = v; dstb[i] = f2b(v); }
}

__global__ void concat_k(const float* __restrict__ te, const float* __restrict__ ve,
                         float* __restrict__ all, unsigned short* __restrict__ allb)
{
    int i = blockIdx.x * blockDim.x + threadIdx.x;
    if (i >= NTOK * 1536) return;
    int r = i / 1536, c = i % 1536;
    float v = (c < 768) ? te[r * 768 + c] : ve[r * 768 + (c - 768)];
    all[i] = v;
    allb[i] = f2b(v);
}

// ---------------------------------------------------------------------------
// head kernels (fp32)
// ---------------------------------------------------------------------------
__global__ __launch_bounds__(256) void head_ac(
    const float* __restrict__ all, const float* __restrict__ lin_w,
    const float* __restrict__ lin_b, float* __restrict__ a, float* __restrict__ c)
{
    const int i = blockIdx.x, t = threadIdx.x;
    const float* xr = all + (long)i * 1536;
    float s0 = 0.f, s1 = 0.f, s2 = 0.f, s3 = 0.f;
    for (int e = t; e < 1536; e += 256) {
        float v = xr[e];
        s0 += v * lin_w[e];
        s1 += v * lin_w[3072 + e];
        s2 += v * lin_w[1536 + e];
        s3 += v * lin_w[4608 + e];
    }
    for (int off = 32; off; off >>= 1) {
        s0 += __shfl_down(s0, off); s1 += __shfl_down(s1, off);
        s2 += __shfl_down(s2, off); s3 += __shfl_down(s3, off);
    }
    __shared__ float r[4][4];
    int w = t >> 6;
    if ((t & 63) == 0) { r[0][w] = s0; r[1][w] = s1; r[2][w] = s2; r[3][w] = s3; }
    __syncthreads();
    if (t == 0) {
        float t0 = 0.f, t1 = 0.f, t2 = 0.f, t3 = 0.f;
        for (int k = 0; k < 4; ++k) { t0 += r[0][k]; t1 += r[1][k]; t2 += r[2][k]; t3 += r[3][k]; }
        a[i * 2 + 0] = t0 + lin_b[0];
        a[i * 2 + 1] = t1 + lin_b[1];
        c[i * 2 + 0] = t2;
        c[i * 2 + 1] = t3;
    }
}

__global__ __launch_bounds__(384) void head_probs(
    const float* __restrict__ a, const float* __restrict__ c,
    const int* __restrict__ gt, float* __restrict__ probs,
    float* __restrict__ rowsum, float* __restrict__ rowcell)
{
    const int i = blockIdx.x, j = threadIdx.x;
    float l0 = a[i * 2 + 0] + c[j * 2 + 0];
    float l1 = a[i * 2 + 1] + c[j * 2 + 1];
    float m = fmaxf(l0, l1);
    float e0 = __expf(l0 - m), e1 = __expf(l1 - m);
    float inv = 1.f / (e0 + e1);
    float p0 = e0 * inv, p1 = e1 * inv;
    long base = ((long)i * NTOK + j) * 2;
    probs[base] = p0;
    probs[base + 1] = p1;
    float m2 = fmaxf(p0, p1);
    float z = m2 + __logf(__expf(p0 - m2) + __expf(p1 - m2));
    int g = gt[i * NTOK + j];
    float cell = z - (g ? p1 : p0);
    float cs = cell, ps = p1;
    for (int off = 32; off; off >>= 1) { cs += __shfl_down(cs, off); ps += __shfl_down(ps, off); }
    __shared__ float rc[6], rs[6];
    int w = j >> 6;
    if ((j & 63) == 0) { rc[w] = cs; rs[w] = ps; }
    __syncthreads();
    if (j == 0) {
        float csum = 0.f, psum = 0.f;
        for (int k = 0; k < 6; ++k) { csum += rc[k]; psum += rs[k]; }
        rowcell[i] = csum * (1.f / NTOK);
        rowsum[i] = psum;
    }
}

__global__ __launch_bounds__(64) void colsum_k(const float* __restrict__ probs,
                                               float* __restrict__ colsum)
{
    const int j = blockIdx.x, t = threadIdx.x;
    float s = 0.f;
    for (int i = t; i < NTOK; i += 64)
        s += probs[((long)i * NTOK + j) * 2 + 1];
    for (int off = 32; off; off >>= 1) s += __shfl_down(s, off);
    if (t == 0) colsum[j] = s;
}

__global__ __launch_bounds__(384) void finalize_k(
    const float* __restrict__ rowcell, const float* __restrict__ rowsum,
    const float* __restrict__ colsum, float* __restrict__ out)
{
    const int t = threadIdx.x;
    float cls = rowcell[t];
    float ee = (t < NTOK - 1) ? fabsf(rowsum[t] + colsum[t] - 1.f) : 0.f;
    for (int off = 32; off; off >>= 1) { cls += __shfl_down(cls, off); ee += __shfl_down(ee, off); }
    __shared__ float rc[6], re[6];
    int w = t >> 6;
    if ((t & 63) == 0) { rc[w] = cls; re[w] = ee; }
    __syncthreads();
    if (t == 0) {
        float a = 0.f, b = 0.f;
        for (int k = 0; k < 6; ++k) { a += rc[k]; b += re[k]; }
        out[NTOK * NTOK * 2 + 0] = a;
        out[NTOK * NTOK * 2 + 1] = b;
    }
}

// ---------------------------------------------------------------------------
// host-side encoder driver (bf16 weights, 64-tile staged gemms)
// ---------------------------------------------------------------------------
static void run_encoder(float* x, unsigned short* xb, int d,
                        const unsigned short* wq, const unsigned short* wo,
                        const unsigned short* w1, const unsigned short* w2,
                        const float* qkv_b, const float* out_b,
                        const float* ln1_s, const float* ln1_b,
                        const float* ff1_b, const float* ff2_b,
                        const float* ln2_s, const float* ln2_b,
                        unsigned short* qkvb, float* sc, unsigned short* attnb,
                        unsigned short* vtb, unsigned short* ob,
                        unsigned short* t1b, float* t2,
                        hipStream_t stream)
{
    const int dq = 3 * d;
    const int hd = d / HEADS;
    const float scale = 1.0f / sqrtf((float)hd);
    for (int l = 0; l < 2; ++l) {
        // qkv = x @ Wqkv^T + b (bf16; V block written transposed to vtb)
        gemm64<<<dim3(dq / 64, 6), 256, 0, stream>>>(
            xb, wq + (long)l * dq * d, qkv_b + l * dq, qkvb,
            d, d, d, dq, 0, 0, 0, 0, 1, vtb, 2 * d);
        // scores = Q @ K^T (fp32), batched over heads
        gemm64<<<dim3(6, 6, HEADS), 256, 0, stream>>>(
            qkvb, qkvb + d, nullptr, sc,
            hd, dq, dq, NTOK, (long)hd, (long)hd, (long)NTOK * NTOK,
            0, 0, nullptr, 0);
        softmax_rows<<<HEADS * NTOK, 64, 0, stream>>>(sc, attnb, scale);
        // o = attn @ V^T (bf16), batched over heads
        gemm64<<<dim3(hd / 64, 6, HEADS), 256, 0, stream>>>(
            attnb, vtb, nullptr, ob,
            NTOK, NTOK, NTOK, d, (long)NTOK * NTOK, (long)hd * NTOK, (long)hd,
            0, 1, nullptr, 0);
        // out-proj (fp32) + LN
        gemm64<<<dim3(d / 64, 6), 256, 0, stream>>>(
            ob, wo + (long)l * d * d, out_b + l * d, t2,
            d, d, d, d, 0, 0, 0, 0, 0, nullptr, 0);
        add_ln<<<NTOK, 256, 0, stream>>>(x, xb, t2, ln1_s + l * d, ln1_b + l * d, d);
        // ff1 (relu, bf16), ff2 (fp32) + LN
        gemm64<<<dim3(2048 / 64, 6), 256, 0, stream>>>(
            xb, w1 + (long)l * 2048 * d, ff1_b + l * 2048, t1b,
            d, d, d, 2048, 0, 0, 0, 1, 1, nullptr, 0);
        gemm64<<<dim3(d / 64, 6), 256, 0, stream>>>(
            t1b, w2 + (long)l * d * 2048, ff2_b + l * d, t2,
            2048, 2048, 2048, d, 0, 0, 0, 0, 0, nullptr, 0);
        add_ln<<<NTOK, 256, 0, stream>>>(x, xb, t2, ln2_s + l * d, ln2_b + l * d, d);
    }
}

extern "C" void kernel_launch(void* const* d_in, const int* in_sizes, int n_in,
                              void* d_out, int out_size, void* d_ws, size_t ws_size,
                              hipStream_t stream)
{
    const float* text_emb   = (const float*)d_in[0];
    const float* vision_emb = (const float*)d_in[1];
    const int*   gt         = (const int*)  d_in[2];
    const float* t_qkv_w = (const float*)d_in[3];
    const float* t_qkv_b = (const float*)d_in[4];
    const float* t_out_w = (const float*)d_in[5];
    const float* t_out_b = (const float*)d_in[6];
    const float* t_ln1_s = (const float*)d_in[7];
    const float* t_ln1_b = (const float*)d_in[8];
    const float* t_ff1_w = (const float*)d_in[9];
    const float* t_ff1_b = (const float*)d_in[10];
    const float* t_ff2_w = (const float*)d_in[11];
    const float* t_ff2_b = (const float*)d_in[12];
    const float* t_ln2_s = (const float*)d_in[13];
    const float* t_ln2_b = (const float*)d_in[14];
    const float* c_qkv_w = (const float*)d_in[15];
    const float* c_qkv_b = (const float*)d_in[16];
    const float* c_out_w = (const float*)d_in[17];
    const float* c_out_b = (const float*)d_in[18];
    const float* c_ln1_s = (const float*)d_in[19];
    const float* c_ln1_b = (const float*)d_in[20];
    const float* c_ff1_w = (const float*)d_in[21];
    const float* c_ff1_b = (const float*)d_in[22];
    const float* c_ff2_w = (const float*)d_in[23];
    const float* c_ff2_b = (const float*)d_in[24];
    const float* c_ln2_s = (const float*)d_in[25];
    const float* c_ln2_b = (const float*)d_in[26];
    const float* lin_w   = (const float*)d_in[27];
    const float* lin_b   = (const float*)d_in[28];
    float* out = (float*)d_out;

    // ---- workspace layout ----
    float* ws = (float*)d_ws;
    float* xt      = ws;                 // 384*768
    float* all     = xt + 294912;        // 384*1536
    float* t2      = all + 589824;       // 384*1536 (max)
    float* sc      = t2 + 589824;        // 4*384*384 fp32
    float* abuf    = sc + 589824;
    float* cbuf    = abuf + 768;
    float* rowsum  = cbuf + 768;
    float* rowcell = rowsum + 384;
    float* colsum  = rowcell + 384;      // fp32 total 2067072
    unsigned short* ub = (unsigned short*)(ws + 2067072);
    unsigned short* xtb   = ub;                  // 294912
    unsigned short* allb  = xtb + 294912;        // 589824
    unsigned short* qkvb  = allb + 589824;       // 384*4608
    unsigned short* attnb = qkvb + 1769472;      // 4*384*384
    unsigned short* vtb   = attnb + 589824;      // 1536*384 (max)
    unsigned short* ob    = vtb + 589824;        // 589824
    unsigned short* t1b   = ob + 589824;         // 384*2048
    unsigned short* wb    = t1b + 786432;        // 42467328 bf16 weights

    // ---- weight conversion (one fused launch) ----
    convert_weights<<<(WTOT / 8 + 255) / 256, 256, 0, stream>>>(
        t_qkv_w, t_out_w, t_ff1_w, t_ff2_w,
        c_qkv_w, c_out_w, c_ff1_w, c_ff2_w, wb);

    // ---- text encoder (d = 768) ----
    initx_k<<<(294912 + 255) / 256, 256, 0, stream>>>(text_emb, xt, xtb, 294912);
    run_encoder(xt, xtb, 768,
                wb + WO0, wb + WO1, wb + WO2, wb + WO3,
                t_qkv_b, t_out_b, t_ln1_s, t_ln1_b,
                t_ff1_b, t_ff2_b, t_ln2_s, t_ln2_b,
                qkvb, sc, attnb, vtb, ob, t1b, t2, stream);

    // ---- concat -> combined encoder (d = 1536) ----
    concat_k<<<(589824 + 255) / 256, 256, 0, stream>>>(xt, vision_emb, all, allb);
    run_encoder(all, allb, 1536,
                wb + WO4, wb + WO5, wb + WO6, wb + WO7,
                c_qkv_b, c_out_b, c_ln1_s, c_ln1_b,
                c_ff1_b, c_ff2_b, c_ln2_s, c_ln2_b,
                qkvb, sc, attnb, vtb, ob, t1b, t2, stream);

    // ---- head ----
    head_ac<<<NTOK, 256, 0, stream>>>(all, lin_w, lin_b, abuf, cbuf);
    head_probs<<<NTOK, 384, 0, stream>>>(abuf, cbuf, gt, out, rowsum, rowcell);
    colsum_k<<<NTOK, 64, 0, stream>>>(out, colsum);
    finalize_k<<<1, 384, 0, stream>>>(rowcell, rowsum, colsum, out);
}